// Round 6
// baseline (298.932 us; speedup 1.0000x reference)
//
#include <hip/hip_runtime.h>

#define NHW 9216   // 96*96
#define NB 2
#define NCHUNK 16  // col chunks for k_simtop

typedef short s8v __attribute__((ext_vector_type(8)));       // 8x16-bit in 4 VGPRs
typedef _Float16 h8v __attribute__((ext_vector_type(8)));    // 8 f16
typedef float f4v __attribute__((ext_vector_type(4)));
typedef unsigned int u32;
typedef unsigned short u16;

__device__ inline u16 f2bf(float x) {
    u32 u = __float_as_uint(x);
    u += 0x7fffu + ((u >> 16) & 1u);          // round-to-nearest-even
    return (u16)(u >> 16);
}
__device__ inline float bf2f(u16 h) {
    return __uint_as_float(((u32)h) << 16);
}

// ---------------------------------------------------------------------------
// K1: conv1 h[g][256] = relu(X^T W1^T + b1) via f16 3-term-split MFMA.
// pad 133: (q*8+j)*133 spreads q across banks (1064 % 32 = 8) -> no 4-way conflict
// ---------------------------------------------------------------------------
__global__ __launch_bounds__(256) void k_gemm1(const float* __restrict__ X,
                                               const float* __restrict__ W1,
                                               const float* __restrict__ b1,
                                               u16* __restrict__ oh, u16* __restrict__ ol)
{
    union SM {
        struct { float A[64 * 133]; u16 B[16 * 512]; } s;  // A: [c][px] pad133; B: frag chunks
        u32 bounce[128 * 65];                              // epilogue transpose buffer
    };
    __shared__ SM sm;
    const int tid = threadIdx.x;
    const int wave = tid >> 6, l = tid & 63, l15 = l & 15, q = l >> 4;
    const int g0 = blockIdx.x * 128;          // global pixel base
    const int c0 = blockIdx.y * 64;           // cout base
    const int bb = g0 / NHW;
    const int hw0 = g0 - bb * NHW;
    const float* Xb = X + (size_t)bb * 384 * NHW;

    f4v acc[2][4];
#pragma unroll
    for (int s = 0; s < 2; ++s)
#pragma unroll
        for (int c = 0; c < 4; ++c) acc[s][c] = (f4v){0.f, 0.f, 0.f, 0.f};

    for (int t = 0; t < 6; ++t) {
        const int kt = t * 64;
        __syncthreads();
#pragma unroll
        for (int r = 0; r < 8; ++r) {
            int idx = r * 256 + tid;
            int cc = idx >> 5, pp = idx & 31;
            *(f4v*)&sm.s.A[cc * 133 + pp * 4] =
                *(const f4v*)&Xb[(size_t)(kt + cc) * NHW + hw0 + pp * 4];
        }
#pragma unroll
        for (int r = 0; r < 2; ++r) {
            int pc = r * 4 + wave;
            int kf = pc >> 2, cs = pc & 3;
            const float* src = W1 + (size_t)(c0 + cs * 16 + l15) * 384 + kt + kf * 32 + q * 8;
            h8v hv, lv;
#pragma unroll
            for (int j = 0; j < 8; ++j) {
                float v = src[j];
                _Float16 h = (_Float16)v;
                hv[j] = h;
                lv[j] = (_Float16)(v - (float)h);
            }
            *(s8v*)&sm.s.B[pc * 512 + l * 8]       = *(s8v*)&hv;
            *(s8v*)&sm.s.B[(8 + pc) * 512 + l * 8] = *(s8v*)&lv;
        }
        __syncthreads();
#pragma unroll
        for (int kf = 0; kf < 2; ++kf) {
            h8v ah[2], al[2];
#pragma unroll
            for (int s = 0; s < 2; ++s) {
#pragma unroll
                for (int j = 0; j < 8; ++j) {
                    float v = sm.s.A[(kf * 32 + q * 8 + j) * 133 + wave * 32 + s * 16 + l15];
                    _Float16 h = (_Float16)v;
                    ah[s][j] = h;
                    al[s][j] = (_Float16)(v - (float)h);
                }
            }
            h8v bh[4], bl[4];
#pragma unroll
            for (int cs = 0; cs < 4; ++cs) {
                bh[cs] = *(const h8v*)&sm.s.B[(kf * 4 + cs) * 512 + l * 8];
                bl[cs] = *(const h8v*)&sm.s.B[(8 + kf * 4 + cs) * 512 + l * 8];
            }
#pragma unroll
            for (int cs = 0; cs < 4; ++cs)
#pragma unroll
                for (int s = 0; s < 2; ++s) {
                    acc[s][cs] = __builtin_amdgcn_mfma_f32_16x16x32_f16(ah[s], bh[cs], acc[s][cs], 0, 0, 0);
                    acc[s][cs] = __builtin_amdgcn_mfma_f32_16x16x32_f16(ah[s], bl[cs], acc[s][cs], 0, 0, 0);
                    acc[s][cs] = __builtin_amdgcn_mfma_f32_16x16x32_f16(al[s], bh[cs], acc[s][cs], 0, 0, 0);
                }
        }
    }
    __syncthreads();

#pragma unroll
    for (int s = 0; s < 2; ++s)
#pragma unroll
        for (int cs = 0; cs < 4; ++cs) {
            int c = cs * 16 + l15;
            float bv = b1[c0 + c];
#pragma unroll
            for (int r = 0; r < 4; ++r) {
                float v = fmaxf(acc[s][cs][r] + bv, 0.f);
                _Float16 h = (_Float16)v;
                _Float16 lo = (_Float16)(v - (float)h);
                int px = wave * 32 + s * 16 + q * 4 + r;
                sm.bounce[px * 65 + c] = (u32)*(u16*)&h | ((u32)*(u16*)&lo << 16);
            }
        }
    __syncthreads();
    {
        int px = tid >> 1, half = tid & 1;
        u16 hb[32], lb[32];
#pragma unroll
        for (int i = 0; i < 32; ++i) {
            u32 p = sm.bounce[px * 65 + half * 32 + i];
            hb[i] = (u16)p; lb[i] = (u16)(p >> 16);
        }
        size_t o = (size_t)(g0 + px) * 256 + c0 + half * 32;
#pragma unroll
        for (int j = 0; j < 4; ++j) {
            *(s8v*)&oh[o + j * 8] = *(s8v*)&hb[j * 8];
            *(s8v*)&ol[o + j * 8] = *(s8v*)&lb[j * 8];
        }
    }
}

// ---------------------------------------------------------------------------
// K2: conv2 feat[g][128] = h W2^T + b2, f16 3-term MFMA, fp32 out. (unchanged)
// ---------------------------------------------------------------------------
__global__ __launch_bounds__(256) void k_gemm2(const u16* __restrict__ hh, const u16* __restrict__ hl,
                                               const float* __restrict__ W2,
                                               const float* __restrict__ b2,
                                               float* __restrict__ feat)
{
    __shared__ u16 Bs[64 * 512];
    const int tid = threadIdx.x;
    const int wave = tid >> 6, l = tid & 63, l15 = l & 15, q = l >> 4;
    const int g0 = blockIdx.x * 64;
    const int c0 = blockIdx.y * 64;

#pragma unroll
    for (int r = 0; r < 8; ++r) {
        int pc = r * 4 + wave;
        int kf = pc >> 2, cs = pc & 3;
        const float* src = W2 + (size_t)(c0 + cs * 16 + l15) * 256 + kf * 32 + q * 8;
        h8v hv, lv;
#pragma unroll
        for (int j = 0; j < 8; ++j) {
            float v = src[j];
            _Float16 h = (_Float16)v;
            hv[j] = h;
            lv[j] = (_Float16)(v - (float)h);
        }
        *(s8v*)&Bs[pc * 512 + l * 8]        = *(s8v*)&hv;
        *(s8v*)&Bs[(32 + pc) * 512 + l * 8] = *(s8v*)&lv;
    }
    __syncthreads();

    const int gw = g0 + wave * 16;
    f4v acc[4];
#pragma unroll
    for (int c = 0; c < 4; ++c) acc[c] = (f4v){0.f, 0.f, 0.f, 0.f};

#pragma unroll
    for (int kf = 0; kf < 8; ++kf) {
        size_t o = (size_t)(gw + l15) * 256 + kf * 32 + q * 8;
        h8v ah = *(const h8v*)&hh[o];
        h8v al = *(const h8v*)&hl[o];
        h8v bh[4], bl[4];
#pragma unroll
        for (int cs = 0; cs < 4; ++cs) {
            bh[cs] = *(const h8v*)&Bs[(kf * 4 + cs) * 512 + l * 8];
            bl[cs] = *(const h8v*)&Bs[(32 + kf * 4 + cs) * 512 + l * 8];
        }
#pragma unroll
        for (int cs = 0; cs < 4; ++cs) {
            acc[cs] = __builtin_amdgcn_mfma_f32_16x16x32_f16(ah, bh[cs], acc[cs], 0, 0, 0);
            acc[cs] = __builtin_amdgcn_mfma_f32_16x16x32_f16(ah, bl[cs], acc[cs], 0, 0, 0);
            acc[cs] = __builtin_amdgcn_mfma_f32_16x16x32_f16(al, bh[cs], acc[cs], 0, 0, 0);
        }
    }
#pragma unroll
    for (int cs = 0; cs < 4; ++cs) {
        float bv = b2[c0 + cs * 16 + l15];
#pragma unroll
        for (int r = 0; r < 4; ++r)
            feat[(size_t)(gw + q * 4 + r) * 128 + c0 + cs * 16 + l15] = acc[cs][r] + bv;
    }
}

// ---------------------------------------------------------------------------
// K3: normalize rows of feat [g][128] -> rf fp32 + bf16 hi/lo (unchanged)
// ---------------------------------------------------------------------------
__global__ __launch_bounds__(256) void k_norm2(const float* __restrict__ feat,
                                               float* __restrict__ rf,
                                               u16* __restrict__ hib, u16* __restrict__ lob)
{
    const int tid = threadIdx.x;
    const int px = blockIdx.x * 64 + (tid >> 2), part = tid & 3;
    const size_t o = (size_t)px * 128 + part * 32;
    f4v v[8];
    float ss = 0.f;
#pragma unroll
    for (int j = 0; j < 8; ++j) {
        v[j] = *(const f4v*)&feat[o + j * 4];
        ss += v[j][0]*v[j][0] + v[j][1]*v[j][1] + v[j][2]*v[j][2] + v[j][3]*v[j][3];
    }
    ss += __shfl_xor(ss, 1, 64);
    ss += __shfl_xor(ss, 2, 64);
    const float mx = fmaxf(sqrtf(ss), 1e-12f);
    u16 hb[32], lb[32];
#pragma unroll
    for (int j = 0; j < 8; ++j) {
        f4v w;
#pragma unroll
        for (int e = 0; e < 4; ++e) {
            float val = v[j][e] / mx;
            w[e] = val;
            u16 h = f2bf(val);
            hb[j * 4 + e] = h;
            lb[j * 4 + e] = f2bf(val - bf2f(h));
        }
        *(f4v*)&rf[o + j * 4] = w;
    }
#pragma unroll
    for (int j = 0; j < 4; ++j) {
        *(s8v*)&hib[o + j * 8] = *(s8v*)&hb[j * 8];
        *(s8v*)&lob[o + j * 8] = *(s8v*)&lb[j * 8];
    }
}

// ---------------------------------------------------------------------------
// K4: sim argmax via 3-term bf16-split MFMA.
// R6: 4 row-subtiles/wave (256 rows/block), sortable-key argmax:
//   acc init = +2.0 -> sims in [1,3], positive floats order as uint;
//   key = (valbits & ~63) | (ct<<2) | cs -> pure umax trees in the hot loop.
// ---------------------------------------------------------------------------
__global__ __launch_bounds__(256, 2) void k_simtop(const u16* __restrict__ hi,
                                                   const u16* __restrict__ lo,
                                                   float* __restrict__ cval,
                                                   int* __restrict__ cidx)
{
    __shared__ u16 Bs[2][32][512];
    const int tid  = threadIdx.x;
    const int wave = tid >> 6, l = tid & 63, l15 = l & 15, q = l >> 4;
    const int b     = blockIdx.z;
    const int rbase = blockIdx.x * 256;
    const int chunk = blockIdx.y;
    const int cbase = chunk * 576;
    const size_t base = (size_t)b * NHW;
    const int wr0 = rbase + wave * 64;

    // A fragments: 4 row-subtiles x 4 k-frags, hi+lo (128 VGPRs)
    s8v ah[4][4], al[4][4];
#pragma unroll
    for (int s = 0; s < 4; ++s) {
        int row = wr0 + s * 16 + l15;
#pragma unroll
        for (int kf = 0; kf < 4; ++kf) {
            int k = kf * 32 + q * 8;
            ah[s][kf] = *(const s8v*)&hi[(base + row) * 128 + k];
            al[s][kf] = *(const s8v*)&lo[(base + row) * 128 + k];
        }
    }

    auto stage = [&](int colt, int buf) {
#pragma unroll
        for (int r = 0; r < 8; ++r) {
            int cid = r * 4 + wave;
            int split = cid >> 4, kf = (cid >> 2) & 3, cs = cid & 3;
            int col = colt + cs * 16 + l15;
            const u16* src = (split ? lo : hi) + (base + col) * 128 + kf * 32 + q * 8;
            __builtin_amdgcn_global_load_lds(
                (const __attribute__((address_space(1))) void*)src,
                (__attribute__((address_space(3))) void*)&Bs[buf][cid][0],
                16, 0, 0);
        }
    };

    u32 bk[4][4];
#pragma unroll
    for (int s = 0; s < 4; ++s)
#pragma unroll
        for (int r = 0; r < 4; ++r) bk[s][r] = 0u;

    stage(cbase, 0);
    __syncthreads();

    for (int ct = 0; ct < 9; ++ct) {
        const int colt = cbase + ct * 64;
        const int buf  = ct & 1;
        if (ct < 8) stage(colt + 64, buf ^ 1);

        f4v acc[4][4];
#pragma unroll
        for (int s = 0; s < 4; ++s)
#pragma unroll
            for (int c = 0; c < 4; ++c) acc[s][c] = (f4v){2.f, 2.f, 2.f, 2.f};

#pragma unroll
        for (int kf = 0; kf < 4; ++kf) {
#pragma unroll
            for (int cs = 0; cs < 4; ++cs) {
                s8v bh = *(const s8v*)&Bs[buf][kf * 4 + cs][l * 8];
                s8v bl = *(const s8v*)&Bs[buf][16 + kf * 4 + cs][l * 8];
#pragma unroll
                for (int s = 0; s < 4; ++s) {
                    acc[s][cs] = __builtin_amdgcn_mfma_f32_16x16x32_bf16(ah[s][kf], bh, acc[s][cs], 0, 0, 0);
                    acc[s][cs] = __builtin_amdgcn_mfma_f32_16x16x32_bf16(ah[s][kf], bl, acc[s][cs], 0, 0, 0);
                    acc[s][cs] = __builtin_amdgcn_mfma_f32_16x16x32_bf16(al[s][kf], bh, acc[s][cs], 0, 0, 0);
                }
            }
        }

        const u32 tagv = (u32)(ct << 2);
        const bool hasdiag = (colt < wr0 + 64) && (wr0 < colt + 64);
        if (hasdiag) {
#pragma unroll
            for (int s = 0; s < 4; ++s)
#pragma unroll
                for (int r = 0; r < 4; ++r) {
                    const int rr = wr0 + s * 16 + q * 4 + r;
                    u32 km = 0u;
#pragma unroll
                    for (int cs = 0; cs < 4; ++cs) {
                        u32 k = (__float_as_uint(acc[s][cs][r]) & 0xffffffc0u) | (tagv | (u32)cs);
                        if (colt + cs * 16 + l15 == rr) k = 0u;
                        km = k > km ? k : km;
                    }
                    bk[s][r] = km > bk[s][r] ? km : bk[s][r];
                }
        } else {
#pragma unroll
            for (int s = 0; s < 4; ++s)
#pragma unroll
                for (int r = 0; r < 4; ++r) {
                    u32 km = 0u;
#pragma unroll
                    for (int cs = 0; cs < 4; ++cs) {
                        u32 k = (__float_as_uint(acc[s][cs][r]) & 0xffffffc0u) | (tagv | (u32)cs);
                        km = k > km ? k : km;
                    }
                    bk[s][r] = km > bk[s][r] ? km : bk[s][r];
                }
        }
        __syncthreads();
    }

    // decode keys, merge (value,col) across the 16 lanes sharing each row
#pragma unroll
    for (int s = 0; s < 4; ++s)
#pragma unroll
        for (int r = 0; r < 4; ++r) {
            u32 key = bk[s][r];
            float v = __uint_as_float(key & 0xffffffc0u);   // biased (+2), masked value
            int ctw = (int)((key >> 2) & 15u);
            int csw = (int)(key & 3u);
            int col = cbase + ctw * 64 + csw * 16 + l15;
#pragma unroll
            for (int d = 1; d < 16; d <<= 1) {
                float ov = __shfl_xor(v, d, 64);
                int   oi = __shfl_xor(col, d, 64);
                bool p = (ov > v) || (ov == v && oi < col);
                v   = p ? ov : v;
                col = p ? oi : col;
            }
            if (l15 == 0) {
                int row = wr0 + s * 16 + q * 4 + r;
                cval[(base + row) * NCHUNK + chunk] = v;
                cidx[(base + row) * NCHUNK + chunk] = col;
            }
        }
}

// ---------------------------------------------------------------------------
// K5: merge candidates (cval is biased+masked but monotone), exact fp32
// distance + mask (unchanged logic)
// ---------------------------------------------------------------------------
__global__ __launch_bounds__(256) void k_finish(const float* __restrict__ rf,
                                                const float* __restrict__ cval,
                                                const int* __restrict__ cidx,
                                                float* __restrict__ out)
{
    const int tid = threadIdx.x;
    const int g = blockIdx.x * 16 + (tid >> 4);
    const int l15 = tid & 15;
    const int b = g / NHW, r = g - b * NHW;

    float bvv = -2.f; int bii = 0;
#pragma unroll
    for (int ch = 0; ch < NCHUNK; ++ch) {
        float v = cval[(size_t)g * NCHUNK + ch];
        int   i = cidx[(size_t)g * NCHUNK + ch];
        bool p = (v > bvv) || (v == bvv && i < bii);
        bvv = p ? v : bvv;
        bii = p ? i : bii;
    }
    const float* x = rf + ((size_t)b * NHW + r)   * 128;
    const float* y = rf + ((size_t)b * NHW + bii) * 128;
    float ss = 0.f;
#pragma unroll
    for (int j = 0; j < 2; ++j) {
        f4v a = *(const f4v*)&x[l15 * 8 + j * 4];
        f4v c = *(const f4v*)&y[l15 * 8 + j * 4];
        float d0 = a[0] - c[0], d1 = a[1] - c[1], d2 = a[2] - c[2], d3 = a[3] - c[3];
        ss += d0 * d0 + d1 * d1 + d2 * d2 + d3 * d3;
    }
#pragma unroll
    for (int d = 1; d < 16; d <<= 1) ss += __shfl_xor(ss, d, 64);
    if (l15 == 0) {
        float dist = sqrtf(ss);
        out[NB * NHW + g] = dist;
        out[g] = dist > 0.2f ? 1.0f : 0.0f;
    }
}

// ===========================================================================
extern "C" void kernel_launch(void* const* d_in, const int* in_sizes, int n_in,
                              void* d_out, int out_size, void* d_ws, size_t ws_size,
                              hipStream_t stream) {
    const float* features = (const float*)d_in[0];
    const float* W1 = (const float*)d_in[1];
    const float* b1 = (const float*)d_in[2];
    const float* W2 = (const float*)d_in[3];
    const float* b2 = (const float*)d_in[4];
    float* out = (float*)d_out;
    float* ws  = (float*)d_ws;

    // ws layout (float offsets), peak 7,077,888 floats = 28,311,552 B:
    //   [0,       2359296)  hh (f16 bits)   -> after gemm2: rf
    //   [2359296, 4718592)  hl (f16 bits)   -> after gemm2: hib/lob (bf16)
    //   [4718592, 7077888)  feat (fp32)     -> after norm2: cval/cidx
    u16*   hh   = (u16*)ws;
    u16*   hl   = (u16*)(ws + 2359296);
    float* feat = ws + 4718592;
    float* rf   = ws;
    u16*   hib  = (u16*)(ws + 2359296);
    u16*   lob  = (u16*)(ws + 3538944);
    float* cval = ws + 4718592;
    int*   cidx = (int*)(ws + 5013504);

    // conv1 (fused transpose + f16 split), M=256 couts
    k_gemm1<<<dim3(144, 4), 256, 0, stream>>>(features, W1, b1, hh, hl);
    // conv2, M=128 couts, fp32 out pixel-major
    k_gemm2<<<dim3(288, 2), 256, 0, stream>>>(hh, hl, W2, b2, feat);
    // L2 normalize + bf16 hi/lo split
    k_norm2<<<288, 256, 0, stream>>>(feat, rf, hib, lob);
    // all-pairs sim + per-row off-diag argmax (16 column chunks of 576)
    k_simtop<<<dim3(36, NCHUNK, NB), 256, 0, stream>>>(hib, lob, cval, cidx);
    // merge + exact distance + mask
    k_finish<<<1152, 256, 0, stream>>>(rf, cval, cidx, out);
}

// Round 7
// 257.844 us; speedup vs baseline: 1.1594x; 1.1594x over previous
//
#include <hip/hip_runtime.h>

#define NHW 9216   // 96*96
#define NB 2
#define NCHUNK 16  // col chunks for k_simtop

typedef short s8v __attribute__((ext_vector_type(8)));       // 8x16-bit in 4 VGPRs
typedef _Float16 h8v __attribute__((ext_vector_type(8)));    // 8 f16
typedef float f4v __attribute__((ext_vector_type(4)));
typedef unsigned int u32;
typedef unsigned short u16;

__device__ inline u16 f2bf(float x) {
    u32 u = __float_as_uint(x);
    u += 0x7fffu + ((u >> 16) & 1u);          // round-to-nearest-even
    return (u16)(u >> 16);
}
__device__ inline float bf2f(u16 h) {
    return __uint_as_float(((u32)h) << 16);
}

// ---------------------------------------------------------------------------
// K1: conv1 h[g][256] = relu(X^T W1^T + b1) via f16 3-term-split MFMA.
// pad 133: (q*8+j)*133 spreads q across banks -> no 4-way conflict
// ---------------------------------------------------------------------------
__global__ __launch_bounds__(256) void k_gemm1(const float* __restrict__ X,
                                               const float* __restrict__ W1,
                                               const float* __restrict__ b1,
                                               u16* __restrict__ oh, u16* __restrict__ ol)
{
    union SM {
        struct { float A[64 * 133]; u16 B[16 * 512]; } s;  // A: [c][px] pad133; B: frag chunks
        u32 bounce[128 * 65];                              // epilogue transpose buffer
    };
    __shared__ SM sm;
    const int tid = threadIdx.x;
    const int wave = tid >> 6, l = tid & 63, l15 = l & 15, q = l >> 4;
    const int g0 = blockIdx.x * 128;          // global pixel base
    const int c0 = blockIdx.y * 64;           // cout base
    const int bb = g0 / NHW;
    const int hw0 = g0 - bb * NHW;
    const float* Xb = X + (size_t)bb * 384 * NHW;

    f4v acc[2][4];
#pragma unroll
    for (int s = 0; s < 2; ++s)
#pragma unroll
        for (int c = 0; c < 4; ++c) acc[s][c] = (f4v){0.f, 0.f, 0.f, 0.f};

    for (int t = 0; t < 6; ++t) {
        const int kt = t * 64;
        __syncthreads();
#pragma unroll
        for (int r = 0; r < 8; ++r) {
            int idx = r * 256 + tid;
            int cc = idx >> 5, pp = idx & 31;
            *(f4v*)&sm.s.A[cc * 133 + pp * 4] =
                *(const f4v*)&Xb[(size_t)(kt + cc) * NHW + hw0 + pp * 4];
        }
#pragma unroll
        for (int r = 0; r < 2; ++r) {
            int pc = r * 4 + wave;
            int kf = pc >> 2, cs = pc & 3;
            const float* src = W1 + (size_t)(c0 + cs * 16 + l15) * 384 + kt + kf * 32 + q * 8;
            h8v hv, lv;
#pragma unroll
            for (int j = 0; j < 8; ++j) {
                float v = src[j];
                _Float16 h = (_Float16)v;
                hv[j] = h;
                lv[j] = (_Float16)(v - (float)h);
            }
            *(s8v*)&sm.s.B[pc * 512 + l * 8]       = *(s8v*)&hv;
            *(s8v*)&sm.s.B[(8 + pc) * 512 + l * 8] = *(s8v*)&lv;
        }
        __syncthreads();
#pragma unroll
        for (int kf = 0; kf < 2; ++kf) {
            h8v ah[2], al[2];
#pragma unroll
            for (int s = 0; s < 2; ++s) {
#pragma unroll
                for (int j = 0; j < 8; ++j) {
                    float v = sm.s.A[(kf * 32 + q * 8 + j) * 133 + wave * 32 + s * 16 + l15];
                    _Float16 h = (_Float16)v;
                    ah[s][j] = h;
                    al[s][j] = (_Float16)(v - (float)h);
                }
            }
            h8v bh[4], bl[4];
#pragma unroll
            for (int cs = 0; cs < 4; ++cs) {
                bh[cs] = *(const h8v*)&sm.s.B[(kf * 4 + cs) * 512 + l * 8];
                bl[cs] = *(const h8v*)&sm.s.B[(8 + kf * 4 + cs) * 512 + l * 8];
            }
#pragma unroll
            for (int cs = 0; cs < 4; ++cs)
#pragma unroll
                for (int s = 0; s < 2; ++s) {
                    acc[s][cs] = __builtin_amdgcn_mfma_f32_16x16x32_f16(ah[s], bh[cs], acc[s][cs], 0, 0, 0);
                    acc[s][cs] = __builtin_amdgcn_mfma_f32_16x16x32_f16(ah[s], bl[cs], acc[s][cs], 0, 0, 0);
                    acc[s][cs] = __builtin_amdgcn_mfma_f32_16x16x32_f16(al[s], bh[cs], acc[s][cs], 0, 0, 0);
                }
        }
    }
    __syncthreads();

#pragma unroll
    for (int s = 0; s < 2; ++s)
#pragma unroll
        for (int cs = 0; cs < 4; ++cs) {
            int c = cs * 16 + l15;
            float bv = b1[c0 + c];
#pragma unroll
            for (int r = 0; r < 4; ++r) {
                float v = fmaxf(acc[s][cs][r] + bv, 0.f);
                _Float16 h = (_Float16)v;
                _Float16 lo = (_Float16)(v - (float)h);
                int px = wave * 32 + s * 16 + q * 4 + r;
                sm.bounce[px * 65 + c] = (u32)*(u16*)&h | ((u32)*(u16*)&lo << 16);
            }
        }
    __syncthreads();
    {
        int px = tid >> 1, half = tid & 1;
        u16 hb[32], lb[32];
#pragma unroll
        for (int i = 0; i < 32; ++i) {
            u32 p = sm.bounce[px * 65 + half * 32 + i];
            hb[i] = (u16)p; lb[i] = (u16)(p >> 16);
        }
        size_t o = (size_t)(g0 + px) * 256 + c0 + half * 32;
#pragma unroll
        for (int j = 0; j < 4; ++j) {
            *(s8v*)&oh[o + j * 8] = *(s8v*)&hb[j * 8];
            *(s8v*)&ol[o + j * 8] = *(s8v*)&lb[j * 8];
        }
    }
}

// ---------------------------------------------------------------------------
// K2: conv2 feat[g][128] = h W2^T + b2, f16 3-term MFMA, fp32 out. (unchanged)
// ---------------------------------------------------------------------------
__global__ __launch_bounds__(256) void k_gemm2(const u16* __restrict__ hh, const u16* __restrict__ hl,
                                               const float* __restrict__ W2,
                                               const float* __restrict__ b2,
                                               float* __restrict__ feat)
{
    __shared__ u16 Bs[64 * 512];
    const int tid = threadIdx.x;
    const int wave = tid >> 6, l = tid & 63, l15 = l & 15, q = l >> 4;
    const int g0 = blockIdx.x * 64;
    const int c0 = blockIdx.y * 64;

#pragma unroll
    for (int r = 0; r < 8; ++r) {
        int pc = r * 4 + wave;
        int kf = pc >> 2, cs = pc & 3;
        const float* src = W2 + (size_t)(c0 + cs * 16 + l15) * 256 + kf * 32 + q * 8;
        h8v hv, lv;
#pragma unroll
        for (int j = 0; j < 8; ++j) {
            float v = src[j];
            _Float16 h = (_Float16)v;
            hv[j] = h;
            lv[j] = (_Float16)(v - (float)h);
        }
        *(s8v*)&Bs[pc * 512 + l * 8]        = *(s8v*)&hv;
        *(s8v*)&Bs[(32 + pc) * 512 + l * 8] = *(s8v*)&lv;
    }
    __syncthreads();

    const int gw = g0 + wave * 16;
    f4v acc[4];
#pragma unroll
    for (int c = 0; c < 4; ++c) acc[c] = (f4v){0.f, 0.f, 0.f, 0.f};

#pragma unroll
    for (int kf = 0; kf < 8; ++kf) {
        size_t o = (size_t)(gw + l15) * 256 + kf * 32 + q * 8;
        h8v ah = *(const h8v*)&hh[o];
        h8v al = *(const h8v*)&hl[o];
        h8v bh[4], bl[4];
#pragma unroll
        for (int cs = 0; cs < 4; ++cs) {
            bh[cs] = *(const h8v*)&Bs[(kf * 4 + cs) * 512 + l * 8];
            bl[cs] = *(const h8v*)&Bs[(32 + kf * 4 + cs) * 512 + l * 8];
        }
#pragma unroll
        for (int cs = 0; cs < 4; ++cs) {
            acc[cs] = __builtin_amdgcn_mfma_f32_16x16x32_f16(ah, bh[cs], acc[cs], 0, 0, 0);
            acc[cs] = __builtin_amdgcn_mfma_f32_16x16x32_f16(ah, bl[cs], acc[cs], 0, 0, 0);
            acc[cs] = __builtin_amdgcn_mfma_f32_16x16x32_f16(al, bh[cs], acc[cs], 0, 0, 0);
        }
    }
#pragma unroll
    for (int cs = 0; cs < 4; ++cs) {
        float bv = b2[c0 + cs * 16 + l15];
#pragma unroll
        for (int r = 0; r < 4; ++r)
            feat[(size_t)(gw + q * 4 + r) * 128 + c0 + cs * 16 + l15] = acc[cs][r] + bv;
    }
}

// ---------------------------------------------------------------------------
// K3: normalize rows of feat [g][128] -> rf fp32 + bf16 hi/lo (unchanged)
// ---------------------------------------------------------------------------
__global__ __launch_bounds__(256) void k_norm2(const float* __restrict__ feat,
                                               float* __restrict__ rf,
                                               u16* __restrict__ hib, u16* __restrict__ lob)
{
    const int tid = threadIdx.x;
    const int px = blockIdx.x * 64 + (tid >> 2), part = tid & 3;
    const size_t o = (size_t)px * 128 + part * 32;
    f4v v[8];
    float ss = 0.f;
#pragma unroll
    for (int j = 0; j < 8; ++j) {
        v[j] = *(const f4v*)&feat[o + j * 4];
        ss += v[j][0]*v[j][0] + v[j][1]*v[j][1] + v[j][2]*v[j][2] + v[j][3]*v[j][3];
    }
    ss += __shfl_xor(ss, 1, 64);
    ss += __shfl_xor(ss, 2, 64);
    const float mx = fmaxf(sqrtf(ss), 1e-12f);
    u16 hb[32], lb[32];
#pragma unroll
    for (int j = 0; j < 8; ++j) {
        f4v w;
#pragma unroll
        for (int e = 0; e < 4; ++e) {
            float val = v[j][e] / mx;
            w[e] = val;
            u16 h = f2bf(val);
            hb[j * 4 + e] = h;
            lb[j * 4 + e] = f2bf(val - bf2f(h));
        }
        *(f4v*)&rf[o + j * 4] = w;
    }
#pragma unroll
    for (int j = 0; j < 4; ++j) {
        *(s8v*)&hib[o + j * 8] = *(s8v*)&hb[j * 8];
        *(s8v*)&lob[o + j * 8] = *(s8v*)&lb[j * 8];
    }
}

// ---------------------------------------------------------------------------
// K4: sim argmax via 3-term bf16-split MFMA.
// R7: back to R5's proven s=3 (192 rows/block, VGPR 116, no spill) + the
// sortable-key argmax: acc init = +2.0 -> sims in [1,3] -> positive floats
// order as uint; key = (valbits & ~63) | (ct<<2) | cs -> pure umax trees.
// ---------------------------------------------------------------------------
__global__ __launch_bounds__(256, 2) void k_simtop(const u16* __restrict__ hi,
                                                   const u16* __restrict__ lo,
                                                   float* __restrict__ cval,
                                                   int* __restrict__ cidx)
{
    __shared__ u16 Bs[2][32][512];
    const int tid  = threadIdx.x;
    const int wave = tid >> 6, l = tid & 63, l15 = l & 15, q = l >> 4;
    const int b     = blockIdx.z;
    const int rbase = blockIdx.x * 192;
    const int chunk = blockIdx.y;
    const int cbase = chunk * 576;
    const size_t base = (size_t)b * NHW;
    const int wr0 = rbase + wave * 48;

    // A fragments: 3 row-subtiles x 4 k-frags, hi+lo (96 VGPRs)
    s8v ah[3][4], al[3][4];
#pragma unroll
    for (int s = 0; s < 3; ++s) {
        int row = wr0 + s * 16 + l15;
#pragma unroll
        for (int kf = 0; kf < 4; ++kf) {
            int k = kf * 32 + q * 8;
            ah[s][kf] = *(const s8v*)&hi[(base + row) * 128 + k];
            al[s][kf] = *(const s8v*)&lo[(base + row) * 128 + k];
        }
    }

    auto stage = [&](int colt, int buf) {
#pragma unroll
        for (int r = 0; r < 8; ++r) {
            int cid = r * 4 + wave;
            int split = cid >> 4, kf = (cid >> 2) & 3, cs = cid & 3;
            int col = colt + cs * 16 + l15;
            const u16* src = (split ? lo : hi) + (base + col) * 128 + kf * 32 + q * 8;
            __builtin_amdgcn_global_load_lds(
                (const __attribute__((address_space(1))) void*)src,
                (__attribute__((address_space(3))) void*)&Bs[buf][cid][0],
                16, 0, 0);
        }
    };

    u32 bk[3][4];
#pragma unroll
    for (int s = 0; s < 3; ++s)
#pragma unroll
        for (int r = 0; r < 4; ++r) bk[s][r] = 0u;

    stage(cbase, 0);
    __syncthreads();

    for (int ct = 0; ct < 9; ++ct) {
        const int colt = cbase + ct * 64;
        const int buf  = ct & 1;
        if (ct < 8) stage(colt + 64, buf ^ 1);

        f4v acc[3][4];
#pragma unroll
        for (int s = 0; s < 3; ++s)
#pragma unroll
            for (int c = 0; c < 4; ++c) acc[s][c] = (f4v){2.f, 2.f, 2.f, 2.f};

#pragma unroll
        for (int kf = 0; kf < 4; ++kf) {
#pragma unroll
            for (int cs = 0; cs < 4; ++cs) {
                s8v bh = *(const s8v*)&Bs[buf][kf * 4 + cs][l * 8];
                s8v bl = *(const s8v*)&Bs[buf][16 + kf * 4 + cs][l * 8];
#pragma unroll
                for (int s = 0; s < 3; ++s) {
                    acc[s][cs] = __builtin_amdgcn_mfma_f32_16x16x32_bf16(ah[s][kf], bh, acc[s][cs], 0, 0, 0);
                    acc[s][cs] = __builtin_amdgcn_mfma_f32_16x16x32_bf16(ah[s][kf], bl, acc[s][cs], 0, 0, 0);
                    acc[s][cs] = __builtin_amdgcn_mfma_f32_16x16x32_bf16(al[s][kf], bh, acc[s][cs], 0, 0, 0);
                }
            }
        }

        const u32 tagv = (u32)(ct << 2);
        const bool hasdiag = (colt < wr0 + 48) && (wr0 < colt + 64);
        if (hasdiag) {
#pragma unroll
            for (int s = 0; s < 3; ++s)
#pragma unroll
                for (int r = 0; r < 4; ++r) {
                    const int rr = wr0 + s * 16 + q * 4 + r;
                    u32 km = 0u;
#pragma unroll
                    for (int cs = 0; cs < 4; ++cs) {
                        u32 k = (__float_as_uint(acc[s][cs][r]) & 0xffffffc0u) | (tagv | (u32)cs);
                        if (colt + cs * 16 + l15 == rr) k = 0u;
                        km = k > km ? k : km;
                    }
                    bk[s][r] = km > bk[s][r] ? km : bk[s][r];
                }
        } else {
#pragma unroll
            for (int s = 0; s < 3; ++s)
#pragma unroll
                for (int r = 0; r < 4; ++r) {
                    u32 km = 0u;
#pragma unroll
                    for (int cs = 0; cs < 4; ++cs) {
                        u32 k = (__float_as_uint(acc[s][cs][r]) & 0xffffffc0u) | (tagv | (u32)cs);
                        km = k > km ? k : km;
                    }
                    bk[s][r] = km > bk[s][r] ? km : bk[s][r];
                }
        }
        __syncthreads();
    }

    // decode keys, merge (value,col) across the 16 lanes sharing each row
#pragma unroll
    for (int s = 0; s < 3; ++s)
#pragma unroll
        for (int r = 0; r < 4; ++r) {
            u32 key = bk[s][r];
            float v = __uint_as_float(key & 0xffffffc0u);   // biased (+2), masked value
            int ctw = (int)((key >> 2) & 15u);
            int csw = (int)(key & 3u);
            int col = cbase + ctw * 64 + csw * 16 + l15;
#pragma unroll
            for (int d = 1; d < 16; d <<= 1) {
                float ov = __shfl_xor(v, d, 64);
                int   oi = __shfl_xor(col, d, 64);
                bool p = (ov > v) || (ov == v && oi < col);
                v   = p ? ov : v;
                col = p ? oi : col;
            }
            if (l15 == 0) {
                int row = wr0 + s * 16 + q * 4 + r;
                cval[(base + row) * NCHUNK + chunk] = v;
                cidx[(base + row) * NCHUNK + chunk] = col;
            }
        }
}

// ---------------------------------------------------------------------------
// K5: merge candidates (cval is biased+masked but monotone), exact fp32
// distance + mask (unchanged)
// ---------------------------------------------------------------------------
__global__ __launch_bounds__(256) void k_finish(const float* __restrict__ rf,
                                                const float* __restrict__ cval,
                                                const int* __restrict__ cidx,
                                                float* __restrict__ out)
{
    const int tid = threadIdx.x;
    const int g = blockIdx.x * 16 + (tid >> 4);
    const int l15 = tid & 15;
    const int b = g / NHW, r = g - b * NHW;

    float bvv = -2.f; int bii = 0;
#pragma unroll
    for (int ch = 0; ch < NCHUNK; ++ch) {
        float v = cval[(size_t)g * NCHUNK + ch];
        int   i = cidx[(size_t)g * NCHUNK + ch];
        bool p = (v > bvv) || (v == bvv && i < bii);
        bvv = p ? v : bvv;
        bii = p ? i : bii;
    }
    const float* x = rf + ((size_t)b * NHW + r)   * 128;
    const float* y = rf + ((size_t)b * NHW + bii) * 128;
    float ss = 0.f;
#pragma unroll
    for (int j = 0; j < 2; ++j) {
        f4v a = *(const f4v*)&x[l15 * 8 + j * 4];
        f4v c = *(const f4v*)&y[l15 * 8 + j * 4];
        float d0 = a[0] - c[0], d1 = a[1] - c[1], d2 = a[2] - c[2], d3 = a[3] - c[3];
        ss += d0 * d0 + d1 * d1 + d2 * d2 + d3 * d3;
    }
#pragma unroll
    for (int d = 1; d < 16; d <<= 1) ss += __shfl_xor(ss, d, 64);
    if (l15 == 0) {
        float dist = sqrtf(ss);
        out[NB * NHW + g] = dist;
        out[g] = dist > 0.2f ? 1.0f : 0.0f;
    }
}

// ===========================================================================
extern "C" void kernel_launch(void* const* d_in, const int* in_sizes, int n_in,
                              void* d_out, int out_size, void* d_ws, size_t ws_size,
                              hipStream_t stream) {
    const float* features = (const float*)d_in[0];
    const float* W1 = (const float*)d_in[1];
    const float* b1 = (const float*)d_in[2];
    const float* W2 = (const float*)d_in[3];
    const float* b2 = (const float*)d_in[4];
    float* out = (float*)d_out;
    float* ws  = (float*)d_ws;

    // ws layout (float offsets), peak 7,077,888 floats = 28,311,552 B:
    //   [0,       2359296)  hh (f16 bits)   -> after gemm2: rf
    //   [2359296, 4718592)  hl (f16 bits)   -> after gemm2: hib/lob (bf16)
    //   [4718592, 7077888)  feat (fp32)     -> after norm2: cval/cidx
    u16*   hh   = (u16*)ws;
    u16*   hl   = (u16*)(ws + 2359296);
    float* feat = ws + 4718592;
    float* rf   = ws;
    u16*   hib  = (u16*)(ws + 2359296);
    u16*   lob  = (u16*)(ws + 3538944);
    float* cval = ws + 4718592;
    int*   cidx = (int*)(ws + 5013504);

    // conv1 (fused transpose + f16 split), M=256 couts
    k_gemm1<<<dim3(144, 4), 256, 0, stream>>>(features, W1, b1, hh, hl);
    // conv2, M=128 couts, fp32 out pixel-major
    k_gemm2<<<dim3(288, 2), 256, 0, stream>>>(hh, hl, W2, b2, feat);
    // L2 normalize + bf16 hi/lo split
    k_norm2<<<288, 256, 0, stream>>>(feat, rf, hib, lob);
    // all-pairs sim + per-row off-diag argmax (16 column chunks of 576)
    k_simtop<<<dim3(48, NCHUNK, NB), 256, 0, stream>>>(hib, lob, cval, cidx);
    // merge + exact distance + mask
    k_finish<<<1152, 256, 0, stream>>>(rf, cval, cidx, out);
}

// Round 8
// 217.187 us; speedup vs baseline: 1.3764x; 1.1872x over previous
//
#include <hip/hip_runtime.h>

#define NHW 9216   // 96*96
#define NB 2
#define NCHUNK 16  // col chunks for k_simtop

typedef short s8v __attribute__((ext_vector_type(8)));       // 8x16-bit in 4 VGPRs
typedef _Float16 h8v __attribute__((ext_vector_type(8)));    // 8 f16
typedef float f4v __attribute__((ext_vector_type(4)));
typedef unsigned int u32;
typedef unsigned short u16;

__device__ inline u16 f2bf(float x) {
    u32 u = __float_as_uint(x);
    u += 0x7fffu + ((u >> 16) & 1u);          // round-to-nearest-even
    return (u16)(u >> 16);
}

// ---------------------------------------------------------------------------
// K1: conv1 h[g][256] = relu(X^T W1^T + b1) via f16 3-term-split MFMA. (R7)
// ---------------------------------------------------------------------------
__global__ __launch_bounds__(256) void k_gemm1(const float* __restrict__ X,
                                               const float* __restrict__ W1,
                                               const float* __restrict__ b1,
                                               u16* __restrict__ oh, u16* __restrict__ ol)
{
    union SM {
        struct { float A[64 * 133]; u16 B[16 * 512]; } s;
        u32 bounce[128 * 65];
    };
    __shared__ SM sm;
    const int tid = threadIdx.x;
    const int wave = tid >> 6, l = tid & 63, l15 = l & 15, q = l >> 4;
    const int g0 = blockIdx.x * 128;
    const int c0 = blockIdx.y * 64;
    const int bb = g0 / NHW;
    const int hw0 = g0 - bb * NHW;
    const float* Xb = X + (size_t)bb * 384 * NHW;

    f4v acc[2][4];
#pragma unroll
    for (int s = 0; s < 2; ++s)
#pragma unroll
        for (int c = 0; c < 4; ++c) acc[s][c] = (f4v){0.f, 0.f, 0.f, 0.f};

    for (int t = 0; t < 6; ++t) {
        const int kt = t * 64;
        __syncthreads();
#pragma unroll
        for (int r = 0; r < 8; ++r) {
            int idx = r * 256 + tid;
            int cc = idx >> 5, pp = idx & 31;
            *(f4v*)&sm.s.A[cc * 133 + pp * 4] =
                *(const f4v*)&Xb[(size_t)(kt + cc) * NHW + hw0 + pp * 4];
        }
#pragma unroll
        for (int r = 0; r < 2; ++r) {
            int pc = r * 4 + wave;
            int kf = pc >> 2, cs = pc & 3;
            const float* src = W1 + (size_t)(c0 + cs * 16 + l15) * 384 + kt + kf * 32 + q * 8;
            h8v hv, lv;
#pragma unroll
            for (int j = 0; j < 8; ++j) {
                float v = src[j];
                _Float16 h = (_Float16)v;
                hv[j] = h;
                lv[j] = (_Float16)(v - (float)h);
            }
            *(s8v*)&sm.s.B[pc * 512 + l * 8]       = *(s8v*)&hv;
            *(s8v*)&sm.s.B[(8 + pc) * 512 + l * 8] = *(s8v*)&lv;
        }
        __syncthreads();
#pragma unroll
        for (int kf = 0; kf < 2; ++kf) {
            h8v ah[2], al[2];
#pragma unroll
            for (int s = 0; s < 2; ++s) {
#pragma unroll
                for (int j = 0; j < 8; ++j) {
                    float v = sm.s.A[(kf * 32 + q * 8 + j) * 133 + wave * 32 + s * 16 + l15];
                    _Float16 h = (_Float16)v;
                    ah[s][j] = h;
                    al[s][j] = (_Float16)(v - (float)h);
                }
            }
            h8v bh[4], bl[4];
#pragma unroll
            for (int cs = 0; cs < 4; ++cs) {
                bh[cs] = *(const h8v*)&sm.s.B[(kf * 4 + cs) * 512 + l * 8];
                bl[cs] = *(const h8v*)&sm.s.B[(8 + kf * 4 + cs) * 512 + l * 8];
            }
#pragma unroll
            for (int cs = 0; cs < 4; ++cs)
#pragma unroll
                for (int s = 0; s < 2; ++s) {
                    acc[s][cs] = __builtin_amdgcn_mfma_f32_16x16x32_f16(ah[s], bh[cs], acc[s][cs], 0, 0, 0);
                    acc[s][cs] = __builtin_amdgcn_mfma_f32_16x16x32_f16(ah[s], bl[cs], acc[s][cs], 0, 0, 0);
                    acc[s][cs] = __builtin_amdgcn_mfma_f32_16x16x32_f16(al[s], bh[cs], acc[s][cs], 0, 0, 0);
                }
        }
    }
    __syncthreads();

#pragma unroll
    for (int s = 0; s < 2; ++s)
#pragma unroll
        for (int cs = 0; cs < 4; ++cs) {
            int c = cs * 16 + l15;
            float bv = b1[c0 + c];
#pragma unroll
            for (int r = 0; r < 4; ++r) {
                float v = fmaxf(acc[s][cs][r] + bv, 0.f);
                _Float16 h = (_Float16)v;
                _Float16 lo = (_Float16)(v - (float)h);
                int px = wave * 32 + s * 16 + q * 4 + r;
                sm.bounce[px * 65 + c] = (u32)*(u16*)&h | ((u32)*(u16*)&lo << 16);
            }
        }
    __syncthreads();
    {
        int px = tid >> 1, half = tid & 1;
        u16 hb[32], lb[32];
#pragma unroll
        for (int i = 0; i < 32; ++i) {
            u32 p = sm.bounce[px * 65 + half * 32 + i];
            hb[i] = (u16)p; lb[i] = (u16)(p >> 16);
        }
        size_t o = (size_t)(g0 + px) * 256 + c0 + half * 32;
#pragma unroll
        for (int j = 0; j < 4; ++j) {
            *(s8v*)&oh[o + j * 8] = *(s8v*)&hb[j * 8];
            *(s8v*)&ol[o + j * 8] = *(s8v*)&lb[j * 8];
        }
    }
}

// ---------------------------------------------------------------------------
// K2: conv2 feat[g][128] = h W2^T + b2, f16 3-term MFMA, fp32 out. (R7)
// ---------------------------------------------------------------------------
__global__ __launch_bounds__(256) void k_gemm2(const u16* __restrict__ hh, const u16* __restrict__ hl,
                                               const float* __restrict__ W2,
                                               const float* __restrict__ b2,
                                               float* __restrict__ feat)
{
    __shared__ u16 Bs[64 * 512];
    const int tid = threadIdx.x;
    const int wave = tid >> 6, l = tid & 63, l15 = l & 15, q = l >> 4;
    const int g0 = blockIdx.x * 64;
    const int c0 = blockIdx.y * 64;

#pragma unroll
    for (int r = 0; r < 8; ++r) {
        int pc = r * 4 + wave;
        int kf = pc >> 2, cs = pc & 3;
        const float* src = W2 + (size_t)(c0 + cs * 16 + l15) * 256 + kf * 32 + q * 8;
        h8v hv, lv;
#pragma unroll
        for (int j = 0; j < 8; ++j) {
            float v = src[j];
            _Float16 h = (_Float16)v;
            hv[j] = h;
            lv[j] = (_Float16)(v - (float)h);
        }
        *(s8v*)&Bs[pc * 512 + l * 8]        = *(s8v*)&hv;
        *(s8v*)&Bs[(32 + pc) * 512 + l * 8] = *(s8v*)&lv;
    }
    __syncthreads();

    const int gw = g0 + wave * 16;
    f4v acc[4];
#pragma unroll
    for (int c = 0; c < 4; ++c) acc[c] = (f4v){0.f, 0.f, 0.f, 0.f};

#pragma unroll
    for (int kf = 0; kf < 8; ++kf) {
        size_t o = (size_t)(gw + l15) * 256 + kf * 32 + q * 8;
        h8v ah = *(const h8v*)&hh[o];
        h8v al = *(const h8v*)&hl[o];
        h8v bh[4], bl[4];
#pragma unroll
        for (int cs = 0; cs < 4; ++cs) {
            bh[cs] = *(const h8v*)&Bs[(kf * 4 + cs) * 512 + l * 8];
            bl[cs] = *(const h8v*)&Bs[(32 + kf * 4 + cs) * 512 + l * 8];
        }
#pragma unroll
        for (int cs = 0; cs < 4; ++cs) {
            acc[cs] = __builtin_amdgcn_mfma_f32_16x16x32_f16(ah, bh[cs], acc[cs], 0, 0, 0);
            acc[cs] = __builtin_amdgcn_mfma_f32_16x16x32_f16(ah, bl[cs], acc[cs], 0, 0, 0);
            acc[cs] = __builtin_amdgcn_mfma_f32_16x16x32_f16(al, bh[cs], acc[cs], 0, 0, 0);
        }
    }
#pragma unroll
    for (int cs = 0; cs < 4; ++cs) {
        float bv = b2[c0 + cs * 16 + l15];
#pragma unroll
        for (int r = 0; r < 4; ++r)
            feat[(size_t)(gw + q * 4 + r) * 128 + c0 + cs * 16 + l15] = acc[cs][r] + bv;
    }
}

// ---------------------------------------------------------------------------
// K3: normalize rows of feat [g][128] -> rf fp32 + bf16 hi (no lo needed now)
// ---------------------------------------------------------------------------
__global__ __launch_bounds__(256) void k_norm2(const float* __restrict__ feat,
                                               float* __restrict__ rf,
                                               u16* __restrict__ hib)
{
    const int tid = threadIdx.x;
    const int px = blockIdx.x * 64 + (tid >> 2), part = tid & 3;
    const size_t o = (size_t)px * 128 + part * 32;
    f4v v[8];
    float ss = 0.f;
#pragma unroll
    for (int j = 0; j < 8; ++j) {
        v[j] = *(const f4v*)&feat[o + j * 4];
        ss += v[j][0]*v[j][0] + v[j][1]*v[j][1] + v[j][2]*v[j][2] + v[j][3]*v[j][3];
    }
    ss += __shfl_xor(ss, 1, 64);
    ss += __shfl_xor(ss, 2, 64);
    const float mx = fmaxf(sqrtf(ss), 1e-12f);
    u16 hb[32];
#pragma unroll
    for (int j = 0; j < 8; ++j) {
        f4v w;
#pragma unroll
        for (int e = 0; e < 4; ++e) {
            float val = v[j][e] / mx;
            w[e] = val;
            hb[j * 4 + e] = f2bf(val);
        }
        *(f4v*)&rf[o + j * 4] = w;
    }
#pragma unroll
    for (int j = 0; j < 4; ++j)
        *(s8v*)&hib[o + j * 8] = *(s8v*)&hb[j * 8];
}

// ---------------------------------------------------------------------------
// K4: sim selection via 1-term bf16 MFMA (selection only; exact re-rank in K5).
// s=4 row-subtiles (64 rows/wave, 256/block); sortable-key argmax
// (acc init +2 -> [1,3] orders as uint; 6 LSBs carry (ct<<2)|cs).
// A: 64 VGPRs (hi only), acc: 64 (AGPR), LDS 2x16KB double buffer.
// ---------------------------------------------------------------------------
__global__ __launch_bounds__(256, 2) void k_simtop(const u16* __restrict__ hi,
                                                   int* __restrict__ cidx)
{
    __shared__ u16 Bs[2][16][512];
    const int tid  = threadIdx.x;
    const int wave = tid >> 6, l = tid & 63, l15 = l & 15, q = l >> 4;
    const int b     = blockIdx.z;
    const int rbase = blockIdx.x * 256;
    const int chunk = blockIdx.y;
    const int cbase = chunk * 576;
    const size_t base = (size_t)b * NHW;
    const int wr0 = rbase + wave * 64;

    // A fragments: 4 row-subtiles x 4 k-frags (64 VGPRs)
    s8v ah[4][4];
#pragma unroll
    for (int s = 0; s < 4; ++s) {
        int row = wr0 + s * 16 + l15;
#pragma unroll
        for (int kf = 0; kf < 4; ++kf)
            ah[s][kf] = *(const s8v*)&hi[(base + row) * 128 + kf * 32 + q * 8];
    }

    auto stage = [&](int colt, int buf) {
#pragma unroll
        for (int r = 0; r < 4; ++r) {
            int cid = r * 4 + wave;                 // cid = kf*4 + cs
            int kf = cid >> 2, cs = cid & 3;
            int col = colt + cs * 16 + l15;
            const u16* src = hi + (base + col) * 128 + kf * 32 + q * 8;
            __builtin_amdgcn_global_load_lds(
                (const __attribute__((address_space(1))) void*)src,
                (__attribute__((address_space(3))) void*)&Bs[buf][cid][0],
                16, 0, 0);
        }
    };

    u32 bk[4][4];
#pragma unroll
    for (int s = 0; s < 4; ++s)
#pragma unroll
        for (int r = 0; r < 4; ++r) bk[s][r] = 0u;

    stage(cbase, 0);
    __syncthreads();

    for (int ct = 0; ct < 9; ++ct) {
        const int colt = cbase + ct * 64;
        const int buf  = ct & 1;
        if (ct < 8) stage(colt + 64, buf ^ 1);

        f4v acc[4][4];
#pragma unroll
        for (int s = 0; s < 4; ++s)
#pragma unroll
            for (int c = 0; c < 4; ++c) acc[s][c] = (f4v){2.f, 2.f, 2.f, 2.f};

#pragma unroll
        for (int kf = 0; kf < 4; ++kf)
#pragma unroll
            for (int cs = 0; cs < 4; ++cs) {
                s8v bh = *(const s8v*)&Bs[buf][kf * 4 + cs][l * 8];
#pragma unroll
                for (int s = 0; s < 4; ++s)
                    acc[s][cs] = __builtin_amdgcn_mfma_f32_16x16x32_bf16(ah[s][kf], bh, acc[s][cs], 0, 0, 0);
            }

        const u32 tagv = (u32)(ct << 2);
        const bool hasdiag = (colt < wr0 + 64) && (wr0 < colt + 64);
        if (hasdiag) {
#pragma unroll
            for (int s = 0; s < 4; ++s)
#pragma unroll
                for (int r = 0; r < 4; ++r) {
                    const int rr = wr0 + s * 16 + q * 4 + r;
                    u32 km = 0u;
#pragma unroll
                    for (int cs = 0; cs < 4; ++cs) {
                        u32 k = (__float_as_uint(acc[s][cs][r]) & 0xffffffc0u) | (tagv | (u32)cs);
                        if (colt + cs * 16 + l15 == rr) k = 0u;
                        km = k > km ? k : km;
                    }
                    bk[s][r] = km > bk[s][r] ? km : bk[s][r];
                }
        } else {
#pragma unroll
            for (int s = 0; s < 4; ++s)
#pragma unroll
                for (int r = 0; r < 4; ++r) {
                    u32 km = 0u;
#pragma unroll
                    for (int cs = 0; cs < 4; ++cs) {
                        u32 k = (__float_as_uint(acc[s][cs][r]) & 0xffffffc0u) | (tagv | (u32)cs);
                        km = k > km ? k : km;
                    }
                    bk[s][r] = km > bk[s][r] ? km : bk[s][r];
                }
        }
        __syncthreads();
    }

    // decode keys, merge (value,col) across 16 lanes per row; write chunk winner idx
#pragma unroll
    for (int s = 0; s < 4; ++s)
#pragma unroll
        for (int r = 0; r < 4; ++r) {
            u32 key = bk[s][r];
            float v = __uint_as_float(key & 0xffffffc0u);
            int ctw = (int)((key >> 2) & 15u);
            int csw = (int)(key & 3u);
            int col = cbase + ctw * 64 + csw * 16 + l15;
#pragma unroll
            for (int d = 1; d < 16; d <<= 1) {
                float ov = __shfl_xor(v, d, 64);
                int   oi = __shfl_xor(col, d, 64);
                bool p = (ov > v) || (ov == v && oi < col);
                v   = p ? ov : v;
                col = p ? oi : col;
            }
            if (l15 == 0) {
                int row = wr0 + s * 16 + q * 4 + r;
                cidx[(base + row) * NCHUNK + chunk] = col;
            }
        }
}

// ---------------------------------------------------------------------------
// K5: exact re-rank of the 16 chunk candidates (fp32 dots from rf), then
// exact diff-based distance + mask. block 256 = 16 rows x 16 lanes.
// ---------------------------------------------------------------------------
__global__ __launch_bounds__(256) void k_finish(const float* __restrict__ rf,
                                                const int* __restrict__ cidx,
                                                float* __restrict__ out)
{
    const int tid = threadIdx.x;
    const int g = blockIdx.x * 16 + (tid >> 4);   // row in [0, 18432)
    const int l15 = tid & 15;
    const int b = g / NHW;
    const size_t rowbase = (size_t)b * NHW;

    const float* x = rf + (size_t)g * 128;
    f4v x0 = *(const f4v*)&x[l15 * 8];
    f4v x1 = *(const f4v*)&x[l15 * 8 + 4];

    float bestS = -2.f; int bestI = 0;
#pragma unroll
    for (int j = 0; j < NCHUNK; ++j) {
        int c = cidx[(size_t)g * NCHUNK + j];
        const float* y = rf + (rowbase + c) * 128;
        f4v y0 = *(const f4v*)&y[l15 * 8];
        f4v y1 = *(const f4v*)&y[l15 * 8 + 4];
        float s = x0[0]*y0[0] + x0[1]*y0[1] + x0[2]*y0[2] + x0[3]*y0[3]
                + x1[0]*y1[0] + x1[1]*y1[1] + x1[2]*y1[2] + x1[3]*y1[3];
#pragma unroll
        for (int d = 1; d < 16; d <<= 1) s += __shfl_xor(s, d, 64);
        bool p = (s > bestS) || (s == bestS && c < bestI);
        bestS = p ? s : bestS;
        bestI = p ? c : bestI;
    }

    const float* y = rf + (rowbase + bestI) * 128;
    f4v y0 = *(const f4v*)&y[l15 * 8];
    f4v y1 = *(const f4v*)&y[l15 * 8 + 4];
    float d0 = x0[0]-y0[0], d1 = x0[1]-y0[1], d2 = x0[2]-y0[2], d3 = x0[3]-y0[3];
    float e0 = x1[0]-y1[0], e1 = x1[1]-y1[1], e2 = x1[2]-y1[2], e3 = x1[3]-y1[3];
    float ss = d0*d0 + d1*d1 + d2*d2 + d3*d3 + e0*e0 + e1*e1 + e2*e2 + e3*e3;
#pragma unroll
    for (int d = 1; d < 16; d <<= 1) ss += __shfl_xor(ss, d, 64);
    if (l15 == 0) {
        float dist = sqrtf(ss);
        out[NB * NHW + g] = dist;                 // distance (B, 9216)
        out[g] = dist > 0.2f ? 1.0f : 0.0f;       // mask (B,1,96,96)
    }
}

// ===========================================================================
extern "C" void kernel_launch(void* const* d_in, const int* in_sizes, int n_in,
                              void* d_out, int out_size, void* d_ws, size_t ws_size,
                              hipStream_t stream) {
    const float* features = (const float*)d_in[0];
    const float* W1 = (const float*)d_in[1];
    const float* b1 = (const float*)d_in[2];
    const float* W2 = (const float*)d_in[3];
    const float* b2 = (const float*)d_in[4];
    float* out = (float*)d_out;
    float* ws  = (float*)d_ws;

    // ws layout (float offsets), peak 7,077,888 floats = 28,311,552 B:
    //   [0,       2359296)  hh (f16 bits)   -> after gemm2: rf
    //   [2359296, 4718592)  hl (f16 bits)   -> after gemm2: hib (bf16, lower half)
    //   [4718592, 7077888)  feat (fp32)     -> after norm2: cidx
    u16*   hh   = (u16*)ws;
    u16*   hl   = (u16*)(ws + 2359296);
    float* feat = ws + 4718592;
    float* rf   = ws;
    u16*   hib  = (u16*)(ws + 2359296);
    int*   cidx = (int*)(ws + 4718592);

    // conv1 (fused transpose + f16 split), M=256 couts
    k_gemm1<<<dim3(144, 4), 256, 0, stream>>>(features, W1, b1, hh, hl);
    // conv2, M=128 couts, fp32 out pixel-major
    k_gemm2<<<dim3(288, 2), 256, 0, stream>>>(hh, hl, W2, b2, feat);
    // L2 normalize + bf16 hi
    k_norm2<<<288, 256, 0, stream>>>(feat, rf, hib);
    // 1-term bf16 sim selection: per-chunk argmax candidates
    k_simtop<<<dim3(36, NCHUNK, NB), 256, 0, stream>>>(hib, cidx);
    // exact fp32 re-rank of 16 candidates + distance + mask
    k_finish<<<1152, 256, 0, stream>>>(rf, cidx, out);
}

// Round 9
// 205.626 us; speedup vs baseline: 1.4538x; 1.0562x over previous
//
#include <hip/hip_runtime.h>

#define NHW 9216   // 96*96
#define NB 2
#define NCHUNK 16  // col chunks for k_simtop

typedef short s8v __attribute__((ext_vector_type(8)));       // 8x16-bit in 4 VGPRs
typedef _Float16 h8v __attribute__((ext_vector_type(8)));    // 8 f16
typedef float f4v __attribute__((ext_vector_type(4)));
typedef unsigned int u32;
typedef unsigned short u16;

__device__ inline u16 f2bf(float x) {
    u32 u = __float_as_uint(x);
    u += 0x7fffu + ((u >> 16) & 1u);          // round-to-nearest-even
    return (u16)(u >> 16);
}
__device__ inline u16 f2h(float x) {
    _Float16 h = (_Float16)x;
    return *(u16*)&h;
}

// ---------------------------------------------------------------------------
// K0a: transpose X [b][384][9216] fp32 -> xh f16 [g][384] (hi only)
// ---------------------------------------------------------------------------
__global__ __launch_bounds__(256) void k_xsplit(const float* __restrict__ X,
                                                u16* __restrict__ xh)
{
    __shared__ float fs[64][65];
    const int tid = threadIdx.x;
    const int b = blockIdx.y, p0 = blockIdx.x * 64;
    const size_t fb = (size_t)b * 384 * NHW;
    const int px = tid >> 2, sub = tid & 3;
    const size_t g = (size_t)b * NHW + p0 + px;
    for (int pass = 0; pass < 6; ++pass) {
        int c0p = pass * 64;
        __syncthreads();
#pragma unroll
        for (int r = 0; r < 16; ++r) {
            int e = r * 256 + tid;
            int cc = e >> 6, p = e & 63;
            fs[cc][p] = X[fb + (size_t)(c0p + cc) * NHW + p0 + p];
        }
        __syncthreads();
        u16 hb[16];
#pragma unroll
        for (int i = 0; i < 16; ++i) hb[i] = f2h(fs[sub * 16 + i][px]);
        size_t o = g * 384 + c0p + sub * 16;
        *(s8v*)&xh[o]     = *(s8v*)&hb[0];
        *(s8v*)&xh[o + 8] = *(s8v*)&hb[8];
    }
}

// ---------------------------------------------------------------------------
// K0b: W1 (98304) + W2 (32768) fp32 -> f16 hi/lo
// ---------------------------------------------------------------------------
__global__ __launch_bounds__(256) void k_wsplit(const float* __restrict__ W1,
                                                const float* __restrict__ W2,
                                                u16* __restrict__ w1h, u16* __restrict__ w1l,
                                                u16* __restrict__ w2h, u16* __restrict__ w2l)
{
    int i = blockIdx.x * 256 + threadIdx.x;
    if (i < 98304) {
        float v = W1[i];
        _Float16 h = (_Float16)v;
        w1h[i] = *(u16*)&h;
        w1l[i] = f2h(v - (float)h);
    } else {
        int j = i - 98304;
        float v = W2[j];
        _Float16 h = (_Float16)v;
        w2h[j] = *(u16*)&h;
        w2l[j] = f2h(v - (float)h);
    }
}

// ---------------------------------------------------------------------------
// K1: conv1 hh[g][256] = relu(xh @ (w1h+w1l)^T + b1), 2-term f16 MFMA.
// 256 px x 64 cout per block; B via global_load_lds double-buffer 2x16KB;
// A = direct s8v loads from xh. XCD swizzle: 4 cout-blocks of one px-group
// land on one XCD (A-tile reused from its L2).
// ---------------------------------------------------------------------------
__global__ __launch_bounds__(256) void k_gemm1(const u16* __restrict__ xh,
                                               const u16* __restrict__ w1h, const u16* __restrict__ w1l,
                                               const float* __restrict__ b1,
                                               u16* __restrict__ hh)
{
    union __align__(16) SM {
        struct { u16 B[2][16][512]; } stg;   // 32 KB staging
        u16 bounce[256 * 66];                // 33.8 KB epilogue transpose
    };
    __shared__ SM sm;
    const int tid = threadIdx.x;
    const int wave = tid >> 6, l = tid & 63, l15 = l & 15, q = l >> 4;
    // swizzle: bx = xcd + 8*k ; px-group = xcd*9 + k/4, cout-block = k%4
    const int bx = blockIdx.x;
    const int xcd = bx & 7, k = bx >> 3;
    const int g0 = (xcd * 9 + (k >> 2)) * 256;
    const int c0 = (k & 3) * 64;
    const int gw = g0 + wave * 64;

    auto stage = [&](int kt, int buf) {
#pragma unroll
        for (int r = 0; r < 4; ++r) {
            int cid = r * 4 + wave;                 // cid = spl*8 + kf*4 + cs
            int spl = cid >> 3, kf = (cid >> 2) & 1, cs = cid & 3;
            const u16* src = (spl ? w1l : w1h) + (size_t)(c0 + cs * 16 + l15) * 384 + kt + kf * 32 + q * 8;
            __builtin_amdgcn_global_load_lds(
                (const __attribute__((address_space(1))) void*)src,
                (__attribute__((address_space(3))) void*)&sm.stg.B[buf][cid][0],
                16, 0, 0);
        }
    };

    f4v acc[4][4];
#pragma unroll
    for (int s = 0; s < 4; ++s)
#pragma unroll
        for (int c = 0; c < 4; ++c) acc[s][c] = (f4v){0.f, 0.f, 0.f, 0.f};

    stage(0, 0);
    __syncthreads();
    for (int t = 0; t < 6; ++t) {
        const int kt = t * 64;
        const int buf = t & 1;
        if (t < 5) stage(kt + 64, buf ^ 1);
        s8v ah[4][2];
#pragma unroll
        for (int s = 0; s < 4; ++s)
#pragma unroll
            for (int kf = 0; kf < 2; ++kf)
                ah[s][kf] = *(const s8v*)&xh[(size_t)(gw + s * 16 + l15) * 384 + kt + kf * 32 + q * 8];
#pragma unroll
        for (int kf = 0; kf < 2; ++kf)
#pragma unroll
            for (int cs = 0; cs < 4; ++cs) {
                s8v bh = *(const s8v*)&sm.stg.B[buf][kf * 4 + cs][l * 8];
                s8v bl = *(const s8v*)&sm.stg.B[buf][8 + kf * 4 + cs][l * 8];
#pragma unroll
                for (int s = 0; s < 4; ++s) {
                    acc[s][cs] = __builtin_amdgcn_mfma_f32_16x16x32_f16(*(h8v*)&ah[s][kf], *(h8v*)&bh, acc[s][cs], 0, 0, 0);
                    acc[s][cs] = __builtin_amdgcn_mfma_f32_16x16x32_f16(*(h8v*)&ah[s][kf], *(h8v*)&bl, acc[s][cs], 0, 0, 0);
                }
            }
        __syncthreads();
    }

    // epilogue: bias+relu, f16, LDS bounce transpose, coalesced [g][256] store
#pragma unroll
    for (int s = 0; s < 4; ++s)
#pragma unroll
        for (int cs = 0; cs < 4; ++cs) {
            int c = cs * 16 + l15;
            float bv = b1[c0 + c];
#pragma unroll
            for (int r = 0; r < 4; ++r) {
                int px = wave * 64 + s * 16 + q * 4 + r;   // C layout: row=q*4+r, col=l15
                sm.bounce[px * 66 + c] = f2h(fmaxf(acc[s][cs][r] + bv, 0.f));
            }
        }
    __syncthreads();
    {
        u32 tmp[32];
#pragma unroll
        for (int j = 0; j < 32; ++j)
            tmp[j] = *(const u32*)&sm.bounce[tid * 66 + j * 2];
        size_t o = (size_t)(g0 + tid) * 256 + c0;
#pragma unroll
        for (int j = 0; j < 8; ++j)
            *(s8v*)&hh[o + j * 8] = *(s8v*)&((u16*)tmp)[j * 8];
    }
}

// ---------------------------------------------------------------------------
// K2: conv2 feat[g][128] = hh @ (w2h+w2l)^T + b2, 2-term f16 MFMA, fp32 out.
// 128 px x 64 cout per block; whole W2 slice staged once via global_load_lds
// (64 KB). XCD swizzle pairs the 2 cout-blocks of one px-group.
// ---------------------------------------------------------------------------
__global__ __launch_bounds__(256) void k_gemm2(const u16* __restrict__ hh,
                                               const u16* __restrict__ w2h, const u16* __restrict__ w2l,
                                               const float* __restrict__ b2,
                                               float* __restrict__ feat)
{
    __shared__ u16 Bs[64][512];   // 64 KB: cid = spl*32 + kf*4 + cs
    const int tid = threadIdx.x;
    const int wave = tid >> 6, l = tid & 63, l15 = l & 15, q = l >> 4;
    const int bx = blockIdx.x;
    const int xcd = bx & 7, k = bx >> 3;
    const int g0 = (xcd * 18 + (k >> 1)) * 128;
    const int c0 = (k & 1) * 64;

#pragma unroll
    for (int r = 0; r < 16; ++r) {
        int cid = r * 4 + wave;
        int spl = cid >> 5, kf = (cid >> 2) & 7, cs = cid & 3;
        const u16* src = (spl ? w2l : w2h) + (size_t)(c0 + cs * 16 + l15) * 256 + kf * 32 + q * 8;
        __builtin_amdgcn_global_load_lds(
            (const __attribute__((address_space(1))) void*)src,
            (__attribute__((address_space(3))) void*)&Bs[cid][0],
            16, 0, 0);
    }
    __syncthreads();

    const int gw = g0 + wave * 32;
    f4v acc[2][4];
#pragma unroll
    for (int s = 0; s < 2; ++s)
#pragma unroll
        for (int c = 0; c < 4; ++c) acc[s][c] = (f4v){0.f, 0.f, 0.f, 0.f};

#pragma unroll
    for (int kf = 0; kf < 8; ++kf) {
        s8v ah[2];
#pragma unroll
        for (int s = 0; s < 2; ++s)
            ah[s] = *(const s8v*)&hh[(size_t)(gw + s * 16 + l15) * 256 + kf * 32 + q * 8];
#pragma unroll
        for (int cs = 0; cs < 4; ++cs) {
            s8v bh = *(const s8v*)&Bs[kf * 4 + cs][l * 8];
            s8v bl = *(const s8v*)&Bs[32 + kf * 4 + cs][l * 8];
#pragma unroll
            for (int s = 0; s < 2; ++s) {
                acc[s][cs] = __builtin_amdgcn_mfma_f32_16x16x32_f16(*(h8v*)&ah[s], *(h8v*)&bh, acc[s][cs], 0, 0, 0);
                acc[s][cs] = __builtin_amdgcn_mfma_f32_16x16x32_f16(*(h8v*)&ah[s], *(h8v*)&bl, acc[s][cs], 0, 0, 0);
            }
        }
    }
#pragma unroll
    for (int s = 0; s < 2; ++s)
#pragma unroll
        for (int cs = 0; cs < 4; ++cs) {
            float bv = b2[c0 + cs * 16 + l15];
#pragma unroll
            for (int r = 0; r < 4; ++r)
                feat[(size_t)(gw + s * 16 + q * 4 + r) * 128 + c0 + cs * 16 + l15] = acc[s][cs][r] + bv;
        }
}

// ---------------------------------------------------------------------------
// K3: normalize rows of feat [g][128] -> rf fp32 + bf16 hi
// ---------------------------------------------------------------------------
__global__ __launch_bounds__(256) void k_norm2(const float* __restrict__ feat,
                                               float* __restrict__ rf,
                                               u16* __restrict__ hib)
{
    const int tid = threadIdx.x;
    const int px = blockIdx.x * 64 + (tid >> 2), part = tid & 3;
    const size_t o = (size_t)px * 128 + part * 32;
    f4v v[8];
    float ss = 0.f;
#pragma unroll
    for (int j = 0; j < 8; ++j) {
        v[j] = *(const f4v*)&feat[o + j * 4];
        ss += v[j][0]*v[j][0] + v[j][1]*v[j][1] + v[j][2]*v[j][2] + v[j][3]*v[j][3];
    }
    ss += __shfl_xor(ss, 1, 64);
    ss += __shfl_xor(ss, 2, 64);
    const float mx = fmaxf(sqrtf(ss), 1e-12f);
    u16 hb[32];
#pragma unroll
    for (int j = 0; j < 8; ++j) {
        f4v w;
#pragma unroll
        for (int e = 0; e < 4; ++e) {
            float val = v[j][e] / mx;
            w[e] = val;
            hb[j * 4 + e] = f2bf(val);
        }
        *(f4v*)&rf[o + j * 4] = w;
    }
#pragma unroll
    for (int j = 0; j < 4; ++j)
        *(s8v*)&hib[o + j * 8] = *(s8v*)&hb[j * 8];
}

// ---------------------------------------------------------------------------
// K4: sim selection via 1-term bf16 MFMA + sortable-key argmax (R8-proven)
// ---------------------------------------------------------------------------
__global__ __launch_bounds__(256, 2) void k_simtop(const u16* __restrict__ hi,
                                                   int* __restrict__ cidx)
{
    __shared__ u16 Bs[2][16][512];
    const int tid  = threadIdx.x;
    const int wave = tid >> 6, l = tid & 63, l15 = l & 15, q = l >> 4;
    const int b     = blockIdx.z;
    const int rbase = blockIdx.x * 256;
    const int chunk = blockIdx.y;
    const int cbase = chunk * 576;
    const size_t base = (size_t)b * NHW;
    const int wr0 = rbase + wave * 64;

    s8v ah[4][4];
#pragma unroll
    for (int s = 0; s < 4; ++s) {
        int row = wr0 + s * 16 + l15;
#pragma unroll
        for (int kf = 0; kf < 4; ++kf)
            ah[s][kf] = *(const s8v*)&hi[(base + row) * 128 + kf * 32 + q * 8];
    }

    auto stage = [&](int colt, int buf) {
#pragma unroll
        for (int r = 0; r < 4; ++r) {
            int cid = r * 4 + wave;
            int kf = cid >> 2, cs = cid & 3;
            int col = colt + cs * 16 + l15;
            const u16* src = hi + (base + col) * 128 + kf * 32 + q * 8;
            __builtin_amdgcn_global_load_lds(
                (const __attribute__((address_space(1))) void*)src,
                (__attribute__((address_space(3))) void*)&Bs[buf][cid][0],
                16, 0, 0);
        }
    };

    u32 bk[4][4];
#pragma unroll
    for (int s = 0; s < 4; ++s)
#pragma unroll
        for (int r = 0; r < 4; ++r) bk[s][r] = 0u;

    stage(cbase, 0);
    __syncthreads();

    for (int ct = 0; ct < 9; ++ct) {
        const int colt = cbase + ct * 64;
        const int buf  = ct & 1;
        if (ct < 8) stage(colt + 64, buf ^ 1);

        f4v acc[4][4];
#pragma unroll
        for (int s = 0; s < 4; ++s)
#pragma unroll
            for (int c = 0; c < 4; ++c) acc[s][c] = (f4v){2.f, 2.f, 2.f, 2.f};

#pragma unroll
        for (int kf = 0; kf < 4; ++kf)
#pragma unroll
            for (int cs = 0; cs < 4; ++cs) {
                s8v bh = *(const s8v*)&Bs[buf][kf * 4 + cs][l * 8];
#pragma unroll
                for (int s = 0; s < 4; ++s)
                    acc[s][cs] = __builtin_amdgcn_mfma_f32_16x16x32_bf16(ah[s][kf], bh, acc[s][cs], 0, 0, 0);
            }

        const u32 tagv = (u32)(ct << 2);
        const bool hasdiag = (colt < wr0 + 64) && (wr0 < colt + 64);
        if (hasdiag) {
#pragma unroll
            for (int s = 0; s < 4; ++s)
#pragma unroll
                for (int r = 0; r < 4; ++r) {
                    const int rr = wr0 + s * 16 + q * 4 + r;
                    u32 km = 0u;
#pragma unroll
                    for (int cs = 0; cs < 4; ++cs) {
                        u32 kk = (__float_as_uint(acc[s][cs][r]) & 0xffffffc0u) | (tagv | (u32)cs);
                        if (colt + cs * 16 + l15 == rr) kk = 0u;
                        km = kk > km ? kk : km;
                    }
                    bk[s][r] = km > bk[s][r] ? km : bk[s][r];
                }
        } else {
#pragma unroll
            for (int s = 0; s < 4; ++s)
#pragma unroll
                for (int r = 0; r < 4; ++r) {
                    u32 km = 0u;
#pragma unroll
                    for (int cs = 0; cs < 4; ++cs) {
                        u32 kk = (__float_as_uint(acc[s][cs][r]) & 0xffffffc0u) | (tagv | (u32)cs);
                        km = kk > km ? kk : km;
                    }
                    bk[s][r] = km > bk[s][r] ? km : bk[s][r];
                }
        }
        __syncthreads();
    }

#pragma unroll
    for (int s = 0; s < 4; ++s)
#pragma unroll
        for (int r = 0; r < 4; ++r) {
            u32 key = bk[s][r];
            float v = __uint_as_float(key & 0xffffffc0u);
            int ctw = (int)((key >> 2) & 15u);
            int csw = (int)(key & 3u);
            int col = cbase + ctw * 64 + csw * 16 + l15;
#pragma unroll
            for (int d = 1; d < 16; d <<= 1) {
                float ov = __shfl_xor(v, d, 64);
                int   oi = __shfl_xor(col, d, 64);
                bool p = (ov > v) || (ov == v && oi < col);
                v   = p ? ov : v;
                col = p ? oi : col;
            }
            if (l15 == 0) {
                int row = wr0 + s * 16 + q * 4 + r;
                cidx[(base + row) * NCHUNK + chunk] = col;
            }
        }
}

// ---------------------------------------------------------------------------
// K5: exact fp32 re-rank of 16 candidates + distance + mask (R8-proven)
// ---------------------------------------------------------------------------
__global__ __launch_bounds__(256) void k_finish(const float* __restrict__ rf,
                                                const int* __restrict__ cidx,
                                                float* __restrict__ out)
{
    const int tid = threadIdx.x;
    const int g = blockIdx.x * 16 + (tid >> 4);
    const int l15 = tid & 15;
    const int b = g / NHW;
    const size_t rowbase = (size_t)b * NHW;

    const float* x = rf + (size_t)g * 128;
    f4v x0 = *(const f4v*)&x[l15 * 8];
    f4v x1 = *(const f4v*)&x[l15 * 8 + 4];

    float bestS = -2.f; int bestI = 0;
#pragma unroll
    for (int j = 0; j < NCHUNK; ++j) {
        int c = cidx[(size_t)g * NCHUNK + j];
        const float* y = rf + (rowbase + c) * 128;
        f4v y0 = *(const f4v*)&y[l15 * 8];
        f4v y1 = *(const f4v*)&y[l15 * 8 + 4];
        float s = x0[0]*y0[0] + x0[1]*y0[1] + x0[2]*y0[2] + x0[3]*y0[3]
                + x1[0]*y1[0] + x1[1]*y1[1] + x1[2]*y1[2] + x1[3]*y1[3];
#pragma unroll
        for (int d = 1; d < 16; d <<= 1) s += __shfl_xor(s, d, 64);
        bool p = (s > bestS) || (s == bestS && c < bestI);
        bestS = p ? s : bestS;
        bestI = p ? c : bestI;
    }

    const float* y = rf + (rowbase + bestI) * 128;
    f4v y0 = *(const f4v*)&y[l15 * 8];
    f4v y1 = *(const f4v*)&y[l15 * 8 + 4];
    float d0 = x0[0]-y0[0], d1 = x0[1]-y0[1], d2 = x0[2]-y0[2], d3 = x0[3]-y0[3];
    float e0 = x1[0]-y1[0], e1 = x1[1]-y1[1], e2 = x1[2]-y1[2], e3 = x1[3]-y1[3];
    float ss = d0*d0 + d1*d1 + d2*d2 + d3*d3 + e0*e0 + e1*e1 + e2*e2 + e3*e3;
#pragma unroll
    for (int d = 1; d < 16; d <<= 1) ss += __shfl_xor(ss, d, 64);
    if (l15 == 0) {
        float dist = sqrtf(ss);
        out[NB * NHW + g] = dist;
        out[g] = dist > 0.2f ? 1.0f : 0.0f;
    }
}

// ===========================================================================
extern "C" void kernel_launch(void* const* d_in, const int* in_sizes, int n_in,
                              void* d_out, int out_size, void* d_ws, size_t ws_size,
                              hipStream_t stream) {
    const float* features = (const float*)d_in[0];
    const float* W1 = (const float*)d_in[1];
    const float* b1 = (const float*)d_in[2];
    const float* W2 = (const float*)d_in[3];
    const float* b2 = (const float*)d_in[4];
    float* out = (float*)d_out;
    float* ws  = (float*)d_ws;

    // ws layout (float offsets), peak 6,029,312 f = 24.1 MB (< proven 28.3 MB):
    //   [0,       3538944)  xh (18432x384 f16)  -> after gemm1: feat [0,2359296) + hib [2359296,3538944)
    //   [3538944, 5898240)  hh (18432x256 f16)  -> after gemm2: rf
    //   [5898240, 6029312)  w1h/w1l/w2h/w2l (f16 weight splits)
    //   cidx aliases feat [0, 294912) after norm2 (feat dead).
    u16*   xh   = (u16*)ws;
    u16*   hh   = (u16*)(ws + 3538944);
    u16*   w1h  = (u16*)(ws + 5898240);
    u16*   w1l  = (u16*)(ws + 5947392);
    u16*   w2h  = (u16*)(ws + 5996544);
    u16*   w2l  = (u16*)(ws + 6012928);
    float* feat = ws;
    u16*   hib  = (u16*)(ws + 2359296);
    float* rf   = ws + 3538944;
    int*   cidx = (int*)ws;

    // transpose + f16 split of X; weight splits
    k_xsplit<<<dim3(144, NB), 256, 0, stream>>>(features, xh);
    k_wsplit<<<512, 256, 0, stream>>>(W1, W2, w1h, w1l, w2h, w2l);
    // conv1 (2-term f16 MFMA, XCD-swizzled)
    k_gemm1<<<288, 256, 0, stream>>>(xh, w1h, w1l, b1, hh);
    // conv2 (2-term f16 MFMA, XCD-swizzled)
    k_gemm2<<<288, 256, 0, stream>>>(hh, w2h, w2l, b2, feat);
    // L2 normalize + bf16 hi
    k_norm2<<<288, 256, 0, stream>>>(feat, rf, hib);
    // 1-term bf16 sim selection: per-chunk argmax candidates
    k_simtop<<<dim3(36, NCHUNK, NB), 256, 0, stream>>>(hib, cidx);
    // exact fp32 re-rank of 16 candidates + distance + mask
    k_finish<<<1152, 256, 0, stream>>>(rf, cidx, out);
}